// Round 5
// baseline (2384.544 us; speedup 1.0000x reference)
//
#include <hip/hip_runtime.h>

#define NUM_USERS 100000
#define NUM_ITEMS 200000
#define EMB_DIM   64
#define NNODES    (NUM_USERS + NUM_ITEMS)   // 300000
#define NNZ_C     10000000
#define BATCH_C   8192

// ---------------------------------------------------------------------------
// 0) zero buffers (no hipMemsetAsync inside kernel_launch — graph capture)
// ---------------------------------------------------------------------------
__global__ void zero_int_kernel(int* __restrict__ p, int n) {
    int i = blockIdx.x * blockDim.x + threadIdx.x;
    if (i < n) p[i] = 0;
}

__global__ void zero_f32_kernel(float* __restrict__ p, long long n) {
    long long i = (long long)blockIdx.x * blockDim.x + threadIdx.x;
    long long stride = (long long)gridDim.x * blockDim.x;
    for (; i < n; i += stride) p[i] = 0.f;
}

// ---------------------------------------------------------------------------
// 1) histogram of row degrees
// ---------------------------------------------------------------------------
__global__ void hist_kernel(const int* __restrict__ rows, int* __restrict__ cnt) {
    int i = blockIdx.x * blockDim.x + threadIdx.x;
    int stride = gridDim.x * blockDim.x;
    for (; i < NNZ_C; i += stride) {
        atomicAdd(&cnt[__builtin_nontemporal_load(rows + i)], 1);
    }
}

// ---------------------------------------------------------------------------
// 2) block-level exclusive scan (1024 elems / block of 256 thr)
// ---------------------------------------------------------------------------
__global__ void scan_a(const int* __restrict__ cnt, int* __restrict__ rp,
                       int* __restrict__ bsum) {
    __shared__ int sm[256];
    int t = threadIdx.x;
    int base = blockIdx.x * 1024 + t * 4;
    int v0 = (base + 0 < NNODES) ? cnt[base + 0] : 0;
    int v1 = (base + 1 < NNODES) ? cnt[base + 1] : 0;
    int v2 = (base + 2 < NNODES) ? cnt[base + 2] : 0;
    int v3 = (base + 3 < NNODES) ? cnt[base + 3] : 0;
    int s = v0 + v1 + v2 + v3;
    sm[t] = s;
    __syncthreads();
    for (int off = 1; off < 256; off <<= 1) {
        int val = (t >= off) ? sm[t - off] : 0;
        __syncthreads();
        sm[t] += val;
        __syncthreads();
    }
    int incl = sm[t];
    int excl = incl - s;
    if (base + 0 < NNODES) rp[base + 0] = excl;
    if (base + 1 < NNODES) rp[base + 1] = excl + v0;
    if (base + 2 < NNODES) rp[base + 2] = excl + v0 + v1;
    if (base + 3 < NNODES) rp[base + 3] = excl + v0 + v1 + v2;
    if (t == 255) bsum[blockIdx.x] = incl;
}

// ---------------------------------------------------------------------------
// 3) scan of block sums (293 entries, single block of 512)
// ---------------------------------------------------------------------------
__global__ void scan_b(int* __restrict__ bsum, int nblk) {
    __shared__ int sm[512];
    int t = threadIdx.x;
    int v = (t < nblk) ? bsum[t] : 0;
    sm[t] = v;
    __syncthreads();
    for (int off = 1; off < 512; off <<= 1) {
        int val = (t >= off) ? sm[t - off] : 0;
        __syncthreads();
        sm[t] += val;
        __syncthreads();
    }
    int excl = sm[t] - v;
    if (t < nblk) bsum[t] = excl;
}

// ---------------------------------------------------------------------------
// 4) finalize row_ptr, init scatter cursors
// ---------------------------------------------------------------------------
__global__ void scan_c(int* __restrict__ rp, const int* __restrict__ bsum,
                       int* __restrict__ cursor) {
    int i = blockIdx.x * blockDim.x + threadIdx.x;
    if (i < NNODES) {
        int v = rp[i] + bsum[i >> 10];
        rp[i] = v;
        cursor[i] = v;
    }
    if (i == 0) rp[NNODES] = NNZ_C;
}

// ---------------------------------------------------------------------------
// 5) scatter edges into CSR order
// ---------------------------------------------------------------------------
__global__ void scatter_kernel(const int* __restrict__ rows,
                               const int* __restrict__ cols,
                               const float* __restrict__ vals,
                               int* __restrict__ cursor,
                               int* __restrict__ ccol,
                               float* __restrict__ cval) {
    int i = blockIdx.x * blockDim.x + threadIdx.x;
    int stride = gridDim.x * blockDim.x;
    for (; i < NNZ_C; i += stride) {
        int r = __builtin_nontemporal_load(rows + i);
        int c = __builtin_nontemporal_load(cols + i);
        float v = __builtin_nontemporal_load(vals + i);
        int pos = atomicAdd(&cursor[r], 1);
        ccol[pos] = c;
        cval[pos] = v;
    }
}

// ---------------------------------------------------------------------------
// 6) row-parallel gather SpMM (CSR path). 16 lanes per row (float4/lane),
//    4 rows/wave, 16 rows per 256-thread block. Full 16-edge chunks take a
//    compile-time-unrolled path (16 independent float4 gathers in flight).
// ---------------------------------------------------------------------------
template <bool FIRST, bool ACCUM>
__global__ __launch_bounds__(256) void spmm_kernel(
        const int* __restrict__ row_ptr, const int* __restrict__ ccol,
        const float* __restrict__ cval, const float* __restrict__ xin,
        const float* __restrict__ uemb, const float* __restrict__ iemb,
        float* __restrict__ xout) {
    int row = blockIdx.x * 16 + (threadIdx.x >> 4);   // 300000/16 = 18750 blocks exact
    int lane = threadIdx.x & 63;
    int dl = lane & 15;            // dim-lane: handles dims [dl*4, dl*4+4)
    int base = lane & 48;          // start lane of this row's 16-lane group

    int start = row_ptr[row];
    int end   = row_ptr[row + 1];

    float ax = 0.f, ay = 0.f, az = 0.f, aw = 0.f;

    int cur = start;
    for (; cur + 16 <= end; cur += 16) {
        int   c = __builtin_nontemporal_load(ccol + cur + dl);
        float v = __builtin_nontemporal_load(cval + cur + dl);
#pragma unroll
        for (int j = 0; j < 16; ++j) {
            int   cj = __shfl(c, base + j);
            float vj = __shfl(v, base + j);
            const float* src;
            if (FIRST) {
                src = (cj < NUM_USERS) ? (uemb + (size_t)cj * EMB_DIM)
                                       : (iemb + (size_t)(cj - NUM_USERS) * EMB_DIM);
            } else {
                src = xin + (size_t)cj * EMB_DIM;
            }
            float4 xv = *reinterpret_cast<const float4*>(src + dl * 4);
            ax += vj * xv.x;
            ay += vj * xv.y;
            az += vj * xv.z;
            aw += vj * xv.w;
        }
    }
    int n = end - cur;
    if (n > 0) {
        int   c = 0;
        float v = 0.f;
        if (dl < n) {
            c = ccol[cur + dl];
            v = cval[cur + dl];
        }
        for (int j = 0; j < n; ++j) {
            int   cj = __shfl(c, base + j);
            float vj = __shfl(v, base + j);
            const float* src;
            if (FIRST) {
                src = (cj < NUM_USERS) ? (uemb + (size_t)cj * EMB_DIM)
                                       : (iemb + (size_t)(cj - NUM_USERS) * EMB_DIM);
            } else {
                src = xin + (size_t)cj * EMB_DIM;
            }
            float4 xv = *reinterpret_cast<const float4*>(src + dl * 4);
            ax += vj * xv.x;
            ay += vj * xv.y;
            az += vj * xv.z;
            aw += vj * xv.w;
        }
    }

    float4* o = reinterpret_cast<float4*>(xout + (size_t)row * EMB_DIM) + dl;
    if (ACCUM) {
        float4 old = *o;
        ax += old.x; ay += old.y; az += old.z; aw += old.w;
    }
    *o = make_float4(ax, ay, az, aw);
}

// ---------------------------------------------------------------------------
// 6b) FALLBACK path (small ws): COO edge-parallel atomic scatter.
// ---------------------------------------------------------------------------
template <bool FIRST>
__global__ __launch_bounds__(256) void coo_spmm_kernel(
        const int* __restrict__ rows, const int* __restrict__ cols,
        const float* __restrict__ vals, const float* __restrict__ xin,
        const float* __restrict__ uemb, const float* __restrict__ iemb,
        float* __restrict__ xout) {
    long long e = (long long)blockIdx.x * 16 + (threadIdx.x >> 4);
    int dl = threadIdx.x & 15;
    if (e >= NNZ_C) return;
    int r = rows[e];
    int c = cols[e];
    float v = vals[e];
    const float* src;
    if (FIRST) {
        src = (c < NUM_USERS) ? (uemb + (size_t)c * EMB_DIM)
                              : (iemb + (size_t)(c - NUM_USERS) * EMB_DIM);
    } else {
        src = xin + (size_t)c * EMB_DIM;
    }
    float4 xv = *reinterpret_cast<const float4*>(src + dl * 4);
    float* dst = xout + (size_t)r * EMB_DIM + dl * 4;
    atomicAdd(dst + 0, v * xv.x);
    atomicAdd(dst + 1, v * xv.y);
    atomicAdd(dst + 2, v * xv.z);
    atomicAdd(dst + 3, v * xv.w);
}

// ---------------------------------------------------------------------------
// 7) final: out[b] = dot(acc_u[u], acc_i[i]) / 16   (acc = x0 + A + B)
//    A = x1 + x3, B = x2. 16 lanes per batch element.
// ---------------------------------------------------------------------------
__global__ __launch_bounds__(256) void dot_kernel(
        const float* __restrict__ uemb, const float* __restrict__ iemb,
        const float* __restrict__ A, const float* __restrict__ B,
        const int* __restrict__ u_idx, const int* __restrict__ i_idx,
        float* __restrict__ out) {
    int t = blockIdx.x * blockDim.x + threadIdx.x;
    int b = t >> 4;
    int dl = t & 15;
    if (b >= BATCH_C) return;

    int u = u_idx[b];
    int ii = i_idx[b];
    size_t uoff  = (size_t)u * EMB_DIM + dl * 4;
    size_t ioff  = (size_t)ii * EMB_DIM + dl * 4;
    size_t Aioff = (size_t)(NUM_USERS + ii) * EMB_DIM + dl * 4;

    float4 e_u = *reinterpret_cast<const float4*>(uemb + uoff);
    float4 a_u = *reinterpret_cast<const float4*>(A + uoff);
    float4 b_u = *reinterpret_cast<const float4*>(B + uoff);
    float4 e_i = *reinterpret_cast<const float4*>(iemb + ioff);
    float4 a_i = *reinterpret_cast<const float4*>(A + Aioff);
    float4 b_i = *reinterpret_cast<const float4*>(B + Aioff);

    float ux = e_u.x + a_u.x + b_u.x, uy = e_u.y + a_u.y + b_u.y;
    float uz = e_u.z + a_u.z + b_u.z, uw = e_u.w + a_u.w + b_u.w;
    float ix = e_i.x + a_i.x + b_i.x, iy = e_i.y + a_i.y + b_i.y;
    float iz = e_i.z + a_i.z + b_i.z, iw = e_i.w + a_i.w + b_i.w;

    float s = ux * ix + uy * iy + uz * iz + uw * iw;
    s += __shfl_xor(s, 1);
    s += __shfl_xor(s, 2);
    s += __shfl_xor(s, 4);
    s += __shfl_xor(s, 8);
    if (dl == 0) out[b] = s * 0.0625f;   // /16 == (acc/4)·(acc/4)
}

// ---------------------------------------------------------------------------
extern "C" void kernel_launch(void* const* d_in, const int* in_sizes, int n_in,
                              void* d_out, int out_size, void* d_ws, size_t ws_size,
                              hipStream_t stream) {
    const float* uemb     = (const float*)d_in[0];
    const float* iemb     = (const float*)d_in[1];
    const float* adj_vals = (const float*)d_in[2];
    const int*   adj_rows = (const int*)d_in[3];
    const int*   adj_cols = (const int*)d_in[4];
    const int*   u_idx    = (const int*)d_in[5];
    const int*   i_idx    = (const int*)d_in[6];
    float* out = (float*)d_out;
    (void)in_sizes; (void)n_in; (void)out_size;

    const size_t DENSE  = (size_t)NNODES * EMB_DIM * sizeof(float);   // 76.8 MB
    const size_t ALIGN  = 256;
    auto rnd = [&](size_t b) { return (b + ALIGN - 1) & ~(ALIGN - 1); };

    const size_t need_full = rnd(DENSE) * 2 + rnd((size_t)NNZ_C * 4) * 2 +
                             rnd((size_t)(NNODES + 1) * 4) + rnd((size_t)NNODES * 4) +
                             rnd(1024 * 4);                            // ~236 MB
    const size_t need_min  = rnd(DENSE) * 2;                           // ~154 MB

    const long long dense_elems = (long long)NNODES * EMB_DIM;
    const int dot_grid = (BATCH_C * 16 + 255) / 256;

    if (ws_size >= need_full) {
        // ------------------- CSR path -------------------
        size_t off = 0;
        auto alloc = [&](size_t bytes) -> void* {
            void* p = (char*)d_ws + off;
            off += rnd(bytes);
            return p;
        };
        float* A       = (float*)alloc(DENSE);
        float* B       = (float*)alloc(DENSE);
        int*   ccol    = (int*)  alloc((size_t)NNZ_C * 4);
        float* cval    = (float*)alloc((size_t)NNZ_C * 4);
        int*   row_ptr = (int*)  alloc((size_t)(NNODES + 1) * 4);
        int*   cursor  = (int*)  alloc((size_t)NNODES * 4);
        int*   bsum    = (int*)  alloc(1024 * 4);

        const int nblk_scan = (NNODES + 1023) / 1024;   // 293

        zero_int_kernel<<<(NNODES + 255) / 256, 256, 0, stream>>>(cursor, NNODES);
        hist_kernel<<<2048, 256, 0, stream>>>(adj_rows, cursor);
        scan_a<<<nblk_scan, 256, 0, stream>>>(cursor, row_ptr, bsum);
        scan_b<<<1, 512, 0, stream>>>(bsum, nblk_scan);
        scan_c<<<(NNODES + 255) / 256, 256, 0, stream>>>(row_ptr, bsum, cursor);
        scatter_kernel<<<2048, 256, 0, stream>>>(adj_rows, adj_cols, adj_vals,
                                                 cursor, ccol, cval);

        const int spmm_grid = NNODES / 16;   // 18750
        spmm_kernel<true,  false><<<spmm_grid, 256, 0, stream>>>(row_ptr, ccol, cval,
                                                                 nullptr, uemb, iemb, A);
        spmm_kernel<false, false><<<spmm_grid, 256, 0, stream>>>(row_ptr, ccol, cval,
                                                                 A, nullptr, nullptr, B);
        spmm_kernel<false, true ><<<spmm_grid, 256, 0, stream>>>(row_ptr, ccol, cval,
                                                                 B, nullptr, nullptr, A);

        dot_kernel<<<dot_grid, 256, 0, stream>>>(uemb, iemb, A, B, u_idx, i_idx, out);
    } else if (ws_size >= need_min) {
        // ------------------- COO atomic fallback (small ws) -------------------
        float* A = (float*)d_ws;                       // x1, then x1+x3
        float* B = (float*)((char*)d_ws + rnd(DENSE)); // x2
        const int coo_grid = (NNZ_C + 15) / 16;        // 16 edges/block

        zero_f32_kernel<<<2048, 256, 0, stream>>>(A, dense_elems);
        coo_spmm_kernel<true ><<<coo_grid, 256, 0, stream>>>(adj_rows, adj_cols, adj_vals,
                                                             nullptr, uemb, iemb, A);
        zero_f32_kernel<<<2048, 256, 0, stream>>>(B, dense_elems);
        coo_spmm_kernel<false><<<coo_grid, 256, 0, stream>>>(adj_rows, adj_cols, adj_vals,
                                                             A, nullptr, nullptr, B);
        coo_spmm_kernel<false><<<coo_grid, 256, 0, stream>>>(adj_rows, adj_cols, adj_vals,
                                                             B, nullptr, nullptr, A);

        dot_kernel<<<dot_grid, 256, 0, stream>>>(uemb, iemb, A, B, u_idx, i_idx, out);
    }
    // else: insufficient workspace — launch nothing; harness reports mismatch
    // (diagnostic outcome rather than a container crash).
}

// Round 7
// 2152.749 us; speedup vs baseline: 1.1077x; 1.1077x over previous
//
#include <hip/hip_runtime.h>

#define NUM_USERS 100000
#define NUM_ITEMS 200000
#define EMB_DIM   64
#define NNODES    (NUM_USERS + NUM_ITEMS)   // 300000
#define NNZ_C     10000000
#define BATCH_C   8192

typedef unsigned long long u64;

// edge record: low 32 bits = col, high 32 bits = val bits
__device__ __forceinline__ u64 pack_edge(int c, float v) {
    return (u64)(unsigned int)c | ((u64)__float_as_uint(v) << 32);
}

// ---------------------------------------------------------------------------
// 0) zero buffers (no hipMemsetAsync inside kernel_launch — graph capture)
// ---------------------------------------------------------------------------
__global__ void zero_int_kernel(int* __restrict__ p, int n) {
    int i = blockIdx.x * blockDim.x + threadIdx.x;
    if (i < n) p[i] = 0;
}

__global__ void zero_f32_kernel(float* __restrict__ p, long long n) {
    long long i = (long long)blockIdx.x * blockDim.x + threadIdx.x;
    long long stride = (long long)gridDim.x * blockDim.x;
    for (; i < n; i += stride) p[i] = 0.f;
}

// ---------------------------------------------------------------------------
// 1) histogram of row degrees
// ---------------------------------------------------------------------------
__global__ void hist_kernel(const int* __restrict__ rows, int* __restrict__ cnt) {
    int i = blockIdx.x * blockDim.x + threadIdx.x;
    int stride = gridDim.x * blockDim.x;
    for (; i < NNZ_C; i += stride) {
        atomicAdd(&cnt[__builtin_nontemporal_load(rows + i)], 1);
    }
}

// ---------------------------------------------------------------------------
// 2) block-level exclusive scan (1024 elems / block of 256 thr)
// ---------------------------------------------------------------------------
__global__ void scan_a(const int* __restrict__ cnt, int* __restrict__ rp,
                       int* __restrict__ bsum) {
    __shared__ int sm[256];
    int t = threadIdx.x;
    int base = blockIdx.x * 1024 + t * 4;
    int v0 = (base + 0 < NNODES) ? cnt[base + 0] : 0;
    int v1 = (base + 1 < NNODES) ? cnt[base + 1] : 0;
    int v2 = (base + 2 < NNODES) ? cnt[base + 2] : 0;
    int v3 = (base + 3 < NNODES) ? cnt[base + 3] : 0;
    int s = v0 + v1 + v2 + v3;
    sm[t] = s;
    __syncthreads();
    for (int off = 1; off < 256; off <<= 1) {
        int val = (t >= off) ? sm[t - off] : 0;
        __syncthreads();
        sm[t] += val;
        __syncthreads();
    }
    int incl = sm[t];
    int excl = incl - s;
    if (base + 0 < NNODES) rp[base + 0] = excl;
    if (base + 1 < NNODES) rp[base + 1] = excl + v0;
    if (base + 2 < NNODES) rp[base + 2] = excl + v0 + v1;
    if (base + 3 < NNODES) rp[base + 3] = excl + v0 + v1 + v2;
    if (t == 255) bsum[blockIdx.x] = incl;
}

// ---------------------------------------------------------------------------
// 3) scan of block sums (293 entries, single block of 512)
// ---------------------------------------------------------------------------
__global__ void scan_b(int* __restrict__ bsum, int nblk) {
    __shared__ int sm[512];
    int t = threadIdx.x;
    int v = (t < nblk) ? bsum[t] : 0;
    sm[t] = v;
    __syncthreads();
    for (int off = 1; off < 512; off <<= 1) {
        int val = (t >= off) ? sm[t - off] : 0;
        __syncthreads();
        sm[t] += val;
        __syncthreads();
    }
    int excl = sm[t] - v;
    if (t < nblk) bsum[t] = excl;
}

// ---------------------------------------------------------------------------
// 4) finalize row_ptr, init scatter cursors
// ---------------------------------------------------------------------------
__global__ void scan_c(int* __restrict__ rp, const int* __restrict__ bsum,
                       int* __restrict__ cursor) {
    int i = blockIdx.x * blockDim.x + threadIdx.x;
    if (i < NNODES) {
        int v = rp[i] + bsum[i >> 10];
        rp[i] = v;
        cursor[i] = v;
    }
    if (i == 0) rp[NNODES] = NNZ_C;
}

// ---------------------------------------------------------------------------
// 5) scatter edges into CSR order — one packed 8 B (col,val) store per edge
//    (was two 4 B stores to two arrays → 927 MB WRITE_SIZE; halving
//    distinct-line-touches should cut that to ~500-600 MB).
// ---------------------------------------------------------------------------
__global__ void scatter_kernel(const int* __restrict__ rows,
                               const int* __restrict__ cols,
                               const float* __restrict__ vals,
                               int* __restrict__ cursor,
                               u64* __restrict__ ccv) {
    int i = blockIdx.x * blockDim.x + threadIdx.x;
    int stride = gridDim.x * blockDim.x;
    for (; i < NNZ_C; i += stride) {
        int r = __builtin_nontemporal_load(rows + i);
        int c = __builtin_nontemporal_load(cols + i);
        float v = __builtin_nontemporal_load(vals + i);
        int pos = atomicAdd(&cursor[r], 1);
        ccv[pos] = pack_edge(c, v);
    }
}

// ---------------------------------------------------------------------------
// 6) row-parallel gather SpMM (CSR path). 16 lanes per row (float4/lane),
//    4 rows/wave, 16 rows per 256-thread block. Full 16-edge chunks take a
//    compile-time-unrolled path (16 independent float4 gathers in flight).
//    Edge stream is the packed u64 (col,val) array.
// ---------------------------------------------------------------------------
template <bool FIRST, bool ACCUM>
__global__ __launch_bounds__(256) void spmm_kernel(
        const int* __restrict__ row_ptr, const u64* __restrict__ ccv,
        const float* __restrict__ xin,
        const float* __restrict__ uemb, const float* __restrict__ iemb,
        float* __restrict__ xout) {
    int row = blockIdx.x * 16 + (threadIdx.x >> 4);   // 300000/16 = 18750 blocks exact
    int lane = threadIdx.x & 63;
    int dl = lane & 15;            // dim-lane: handles dims [dl*4, dl*4+4)
    int base = lane & 48;          // start lane of this row's 16-lane group

    int start = row_ptr[row];
    int end   = row_ptr[row + 1];

    float ax = 0.f, ay = 0.f, az = 0.f, aw = 0.f;

    int cur = start;
    for (; cur + 16 <= end; cur += 16) {
        u64 e = __builtin_nontemporal_load(ccv + cur + dl);
        int   c = (int)(unsigned int)(e & 0xffffffffu);
        float v = __uint_as_float((unsigned int)(e >> 32));
#pragma unroll
        for (int j = 0; j < 16; ++j) {
            int   cj = __shfl(c, base + j);
            float vj = __shfl(v, base + j);
            const float* src;
            if (FIRST) {
                src = (cj < NUM_USERS) ? (uemb + (size_t)cj * EMB_DIM)
                                       : (iemb + (size_t)(cj - NUM_USERS) * EMB_DIM);
            } else {
                src = xin + (size_t)cj * EMB_DIM;
            }
            float4 xv = *reinterpret_cast<const float4*>(src + dl * 4);
            ax += vj * xv.x;
            ay += vj * xv.y;
            az += vj * xv.z;
            aw += vj * xv.w;
        }
    }
    int n = end - cur;
    if (n > 0) {
        int   c = 0;
        float v = 0.f;
        if (dl < n) {
            u64 e = ccv[cur + dl];
            c = (int)(unsigned int)(e & 0xffffffffu);
            v = __uint_as_float((unsigned int)(e >> 32));
        }
        for (int j = 0; j < n; ++j) {
            int   cj = __shfl(c, base + j);
            float vj = __shfl(v, base + j);
            const float* src;
            if (FIRST) {
                src = (cj < NUM_USERS) ? (uemb + (size_t)cj * EMB_DIM)
                                       : (iemb + (size_t)(cj - NUM_USERS) * EMB_DIM);
            } else {
                src = xin + (size_t)cj * EMB_DIM;
            }
            float4 xv = *reinterpret_cast<const float4*>(src + dl * 4);
            ax += vj * xv.x;
            ay += vj * xv.y;
            az += vj * xv.z;
            aw += vj * xv.w;
        }
    }

    float4* o = reinterpret_cast<float4*>(xout + (size_t)row * EMB_DIM) + dl;
    if (ACCUM) {
        float4 old = *o;
        ax += old.x; ay += old.y; az += old.z; aw += old.w;
    }
    *o = make_float4(ax, ay, az, aw);
}

// ---------------------------------------------------------------------------
// 6b) FALLBACK path (small ws): COO edge-parallel atomic scatter.
// ---------------------------------------------------------------------------
template <bool FIRST>
__global__ __launch_bounds__(256) void coo_spmm_kernel(
        const int* __restrict__ rows, const int* __restrict__ cols,
        const float* __restrict__ vals, const float* __restrict__ xin,
        const float* __restrict__ uemb, const float* __restrict__ iemb,
        float* __restrict__ xout) {
    long long e = (long long)blockIdx.x * 16 + (threadIdx.x >> 4);
    int dl = threadIdx.x & 15;
    if (e >= NNZ_C) return;
    int r = rows[e];
    int c = cols[e];
    float v = vals[e];
    const float* src;
    if (FIRST) {
        src = (c < NUM_USERS) ? (uemb + (size_t)c * EMB_DIM)
                              : (iemb + (size_t)(c - NUM_USERS) * EMB_DIM);
    } else {
        src = xin + (size_t)c * EMB_DIM;
    }
    float4 xv = *reinterpret_cast<const float4*>(src + dl * 4);
    float* dst = xout + (size_t)r * EMB_DIM + dl * 4;
    atomicAdd(dst + 0, v * xv.x);
    atomicAdd(dst + 1, v * xv.y);
    atomicAdd(dst + 2, v * xv.z);
    atomicAdd(dst + 3, v * xv.w);
}

// ---------------------------------------------------------------------------
// 7) final: out[b] = dot(acc_u[u], acc_i[i]) / 16   (acc = x0 + A + B)
//    A = x1 + x3, B = x2. 16 lanes per batch element.
// ---------------------------------------------------------------------------
__global__ __launch_bounds__(256) void dot_kernel(
        const float* __restrict__ uemb, const float* __restrict__ iemb,
        const float* __restrict__ A, const float* __restrict__ B,
        const int* __restrict__ u_idx, const int* __restrict__ i_idx,
        float* __restrict__ out) {
    int t = blockIdx.x * blockDim.x + threadIdx.x;
    int b = t >> 4;
    int dl = t & 15;
    if (b >= BATCH_C) return;

    int u = u_idx[b];
    int ii = i_idx[b];
    size_t uoff  = (size_t)u * EMB_DIM + dl * 4;
    size_t ioff  = (size_t)ii * EMB_DIM + dl * 4;
    size_t Aioff = (size_t)(NUM_USERS + ii) * EMB_DIM + dl * 4;

    float4 e_u = *reinterpret_cast<const float4*>(uemb + uoff);
    float4 a_u = *reinterpret_cast<const float4*>(A + uoff);
    float4 b_u = *reinterpret_cast<const float4*>(B + uoff);
    float4 e_i = *reinterpret_cast<const float4*>(iemb + ioff);
    float4 a_i = *reinterpret_cast<const float4*>(A + Aioff);
    float4 b_i = *reinterpret_cast<const float4*>(B + Aioff);

    float ux = e_u.x + a_u.x + b_u.x, uy = e_u.y + a_u.y + b_u.y;
    float uz = e_u.z + a_u.z + b_u.z, uw = e_u.w + a_u.w + b_u.w;
    float ix = e_i.x + a_i.x + b_i.x, iy = e_i.y + a_i.y + b_i.y;
    float iz = e_i.z + a_i.z + b_i.z, iw = e_i.w + a_i.w + b_i.w;

    float s = ux * ix + uy * iy + uz * iz + uw * iw;
    s += __shfl_xor(s, 1);
    s += __shfl_xor(s, 2);
    s += __shfl_xor(s, 4);
    s += __shfl_xor(s, 8);
    if (dl == 0) out[b] = s * 0.0625f;   // /16 == (acc/4)·(acc/4)
}

// ---------------------------------------------------------------------------
extern "C" void kernel_launch(void* const* d_in, const int* in_sizes, int n_in,
                              void* d_out, int out_size, void* d_ws, size_t ws_size,
                              hipStream_t stream) {
    const float* uemb     = (const float*)d_in[0];
    const float* iemb     = (const float*)d_in[1];
    const float* adj_vals = (const float*)d_in[2];
    const int*   adj_rows = (const int*)d_in[3];
    const int*   adj_cols = (const int*)d_in[4];
    const int*   u_idx    = (const int*)d_in[5];
    const int*   i_idx    = (const int*)d_in[6];
    float* out = (float*)d_out;
    (void)in_sizes; (void)n_in; (void)out_size;

    const size_t DENSE  = (size_t)NNODES * EMB_DIM * sizeof(float);   // 76.8 MB
    const size_t ALIGN  = 256;
    auto rnd = [&](size_t b) { return (b + ALIGN - 1) & ~(ALIGN - 1); };

    const size_t need_full = rnd(DENSE) * 2 + rnd((size_t)NNZ_C * 8) +
                             rnd((size_t)(NNODES + 1) * 4) + rnd((size_t)NNODES * 4) +
                             rnd(1024 * 4);                            // ~236 MB
    const size_t need_min  = rnd(DENSE) * 2;                           // ~154 MB

    const long long dense_elems = (long long)NNODES * EMB_DIM;
    const int dot_grid = (BATCH_C * 16 + 255) / 256;

    if (ws_size >= need_full) {
        // ------------------- CSR path -------------------
        size_t off = 0;
        auto alloc = [&](size_t bytes) -> void* {
            void* p = (char*)d_ws + off;
            off += rnd(bytes);
            return p;
        };
        float* A       = (float*)alloc(DENSE);
        float* B       = (float*)alloc(DENSE);
        u64*   ccv     = (u64*)  alloc((size_t)NNZ_C * 8);
        int*   row_ptr = (int*)  alloc((size_t)(NNODES + 1) * 4);
        int*   cursor  = (int*)  alloc((size_t)NNODES * 4);
        int*   bsum    = (int*)  alloc(1024 * 4);

        const int nblk_scan = (NNODES + 1023) / 1024;   // 293

        zero_int_kernel<<<(NNODES + 255) / 256, 256, 0, stream>>>(cursor, NNODES);
        hist_kernel<<<2048, 256, 0, stream>>>(adj_rows, cursor);
        scan_a<<<nblk_scan, 256, 0, stream>>>(cursor, row_ptr, bsum);
        scan_b<<<1, 512, 0, stream>>>(bsum, nblk_scan);
        scan_c<<<(NNODES + 255) / 256, 256, 0, stream>>>(row_ptr, bsum, cursor);
        scatter_kernel<<<2048, 256, 0, stream>>>(adj_rows, adj_cols, adj_vals,
                                                 cursor, ccv);

        const int spmm_grid = NNODES / 16;   // 18750
        spmm_kernel<true,  false><<<spmm_grid, 256, 0, stream>>>(row_ptr, ccv,
                                                                 nullptr, uemb, iemb, A);
        spmm_kernel<false, false><<<spmm_grid, 256, 0, stream>>>(row_ptr, ccv,
                                                                 A, nullptr, nullptr, B);
        spmm_kernel<false, true ><<<spmm_grid, 256, 0, stream>>>(row_ptr, ccv,
                                                                 B, nullptr, nullptr, A);

        dot_kernel<<<dot_grid, 256, 0, stream>>>(uemb, iemb, A, B, u_idx, i_idx, out);
    } else if (ws_size >= need_min) {
        // ------------------- COO atomic fallback (small ws) -------------------
        float* A = (float*)d_ws;                       // x1, then x1+x3
        float* B = (float*)((char*)d_ws + rnd(DENSE)); // x2
        const int coo_grid = (NNZ_C + 15) / 16;        // 16 edges/block

        zero_f32_kernel<<<2048, 256, 0, stream>>>(A, dense_elems);
        coo_spmm_kernel<true ><<<coo_grid, 256, 0, stream>>>(adj_rows, adj_cols, adj_vals,
                                                             nullptr, uemb, iemb, A);
        zero_f32_kernel<<<2048, 256, 0, stream>>>(B, dense_elems);
        coo_spmm_kernel<false><<<coo_grid, 256, 0, stream>>>(adj_rows, adj_cols, adj_vals,
                                                             A, nullptr, nullptr, B);
        coo_spmm_kernel<false><<<coo_grid, 256, 0, stream>>>(adj_rows, adj_cols, adj_vals,
                                                             B, nullptr, nullptr, A);

        dot_kernel<<<dot_grid, 256, 0, stream>>>(uemb, iemb, A, B, u_idx, i_idx, out);
    }
    // else: insufficient workspace — launch nothing; harness reports mismatch
    // (diagnostic outcome rather than a container crash).
}

// Round 8
// 1650.298 us; speedup vs baseline: 1.4449x; 1.3045x over previous
//
#include <hip/hip_runtime.h>

#define NUM_USERS 100000
#define NUM_ITEMS 200000
#define EMB_DIM   64
#define NNODES    (NUM_USERS + NUM_ITEMS)   // 300000
#define NNZ_C     10000000
#define BATCH_C   8192

typedef unsigned long long u64;

// edge record: low 32 bits = col, high 32 bits = val bits
__device__ __forceinline__ u64 pack_edge(int c, float v) {
    return (u64)(unsigned int)c | ((u64)__float_as_uint(v) << 32);
}

// bf16 helpers (RNE round, exact widen)
__device__ __forceinline__ unsigned short f2bf(float f) {
    unsigned u = __float_as_uint(f);
    u += 0x7fffu + ((u >> 16) & 1u);
    return (unsigned short)(u >> 16);
}
__device__ __forceinline__ float bf2f(unsigned short h) {
    return __uint_as_float((unsigned)h << 16);
}

// ---------------------------------------------------------------------------
// 0) zero buffers (no hipMemsetAsync inside kernel_launch — graph capture)
// ---------------------------------------------------------------------------
__global__ void zero_int_kernel(int* __restrict__ p, int n) {
    int i = blockIdx.x * blockDim.x + threadIdx.x;
    if (i < n) p[i] = 0;
}

__global__ void zero_f32_kernel(float* __restrict__ p, long long n) {
    long long i = (long long)blockIdx.x * blockDim.x + threadIdx.x;
    long long stride = (long long)gridDim.x * blockDim.x;
    for (; i < n; i += stride) p[i] = 0.f;
}

// ---------------------------------------------------------------------------
// 0b) convert x0 = concat(uemb, iemb) to bf16 (halves all gather traffic)
// ---------------------------------------------------------------------------
__global__ void convert_x0_kernel(const float* __restrict__ uemb,
                                  const float* __restrict__ iemb,
                                  ushort* __restrict__ x0) {
    const long long total4 = (long long)NNODES * EMB_DIM / 4;   // 4.8M float4 groups
    const long long usr4   = (long long)NUM_USERS * EMB_DIM / 4;
    long long g = (long long)blockIdx.x * blockDim.x + threadIdx.x;
    long long stride = (long long)gridDim.x * blockDim.x;
    for (; g < total4; g += stride) {
        long long base = g * 4;
        const float* src = (g < usr4) ? (uemb + base)
                                      : (iemb + (base - (long long)NUM_USERS * EMB_DIM));
        float4 v = *reinterpret_cast<const float4*>(src);
        ushort4 o = make_ushort4(f2bf(v.x), f2bf(v.y), f2bf(v.z), f2bf(v.w));
        *reinterpret_cast<ushort4*>(x0 + base) = o;
    }
}

// ---------------------------------------------------------------------------
// 1) histogram of row degrees
// ---------------------------------------------------------------------------
__global__ void hist_kernel(const int* __restrict__ rows, int* __restrict__ cnt) {
    int i = blockIdx.x * blockDim.x + threadIdx.x;
    int stride = gridDim.x * blockDim.x;
    for (; i < NNZ_C; i += stride) {
        atomicAdd(&cnt[__builtin_nontemporal_load(rows + i)], 1);
    }
}

// ---------------------------------------------------------------------------
// 2) block-level exclusive scan (1024 elems / block of 256 thr)
// ---------------------------------------------------------------------------
__global__ void scan_a(const int* __restrict__ cnt, int* __restrict__ rp,
                       int* __restrict__ bsum) {
    __shared__ int sm[256];
    int t = threadIdx.x;
    int base = blockIdx.x * 1024 + t * 4;
    int v0 = (base + 0 < NNODES) ? cnt[base + 0] : 0;
    int v1 = (base + 1 < NNODES) ? cnt[base + 1] : 0;
    int v2 = (base + 2 < NNODES) ? cnt[base + 2] : 0;
    int v3 = (base + 3 < NNODES) ? cnt[base + 3] : 0;
    int s = v0 + v1 + v2 + v3;
    sm[t] = s;
    __syncthreads();
    for (int off = 1; off < 256; off <<= 1) {
        int val = (t >= off) ? sm[t - off] : 0;
        __syncthreads();
        sm[t] += val;
        __syncthreads();
    }
    int incl = sm[t];
    int excl = incl - s;
    if (base + 0 < NNODES) rp[base + 0] = excl;
    if (base + 1 < NNODES) rp[base + 1] = excl + v0;
    if (base + 2 < NNODES) rp[base + 2] = excl + v0 + v1;
    if (base + 3 < NNODES) rp[base + 3] = excl + v0 + v1 + v2;
    if (t == 255) bsum[blockIdx.x] = incl;
}

// ---------------------------------------------------------------------------
// 3) scan of block sums (293 entries, single block of 512)
// ---------------------------------------------------------------------------
__global__ void scan_b(int* __restrict__ bsum, int nblk) {
    __shared__ int sm[512];
    int t = threadIdx.x;
    int v = (t < nblk) ? bsum[t] : 0;
    sm[t] = v;
    __syncthreads();
    for (int off = 1; off < 512; off <<= 1) {
        int val = (t >= off) ? sm[t - off] : 0;
        __syncthreads();
        sm[t] += val;
        __syncthreads();
    }
    int excl = sm[t] - v;
    if (t < nblk) bsum[t] = excl;
}

// ---------------------------------------------------------------------------
// 4) finalize row_ptr, init scatter cursors
// ---------------------------------------------------------------------------
__global__ void scan_c(int* __restrict__ rp, const int* __restrict__ bsum,
                       int* __restrict__ cursor) {
    int i = blockIdx.x * blockDim.x + threadIdx.x;
    if (i < NNODES) {
        int v = rp[i] + bsum[i >> 10];
        rp[i] = v;
        cursor[i] = v;
    }
    if (i == 0) rp[NNODES] = NNZ_C;
}

// ---------------------------------------------------------------------------
// 5) scatter edges into CSR order — one packed 8 B (col,val) store per edge.
//    At the random-single-record floor (~64 B line per edge = 619 MB measured).
// ---------------------------------------------------------------------------
__global__ void scatter_kernel(const int* __restrict__ rows,
                               const int* __restrict__ cols,
                               const float* __restrict__ vals,
                               int* __restrict__ cursor,
                               u64* __restrict__ ccv) {
    int i = blockIdx.x * blockDim.x + threadIdx.x;
    int stride = gridDim.x * blockDim.x;
    for (; i < NNZ_C; i += stride) {
        int r = __builtin_nontemporal_load(rows + i);
        int c = __builtin_nontemporal_load(cols + i);
        float v = __builtin_nontemporal_load(vals + i);
        int pos = atomicAdd(&cursor[r], 1);
        ccv[pos] = pack_edge(c, v);
    }
}

// ---------------------------------------------------------------------------
// 6) row-parallel gather SpMM, bf16 state. 16 lanes per row (ushort4/lane =
//    4 dims), 4 rows/wave, 16 rows per 256-thread block. f32 accumulate,
//    bf16 write. ACCUM: xout[row] += result (layer 3: A becomes x1+x3).
// ---------------------------------------------------------------------------
template <bool ACCUM>
__global__ __launch_bounds__(256) void spmm_bf_kernel(
        const int* __restrict__ row_ptr, const u64* __restrict__ ccv,
        const ushort* __restrict__ xin, ushort* __restrict__ xout) {
    int row = blockIdx.x * 16 + (threadIdx.x >> 4);   // 300000/16 = 18750 blocks exact
    int lane = threadIdx.x & 63;
    int dl = lane & 15;            // dim-lane: handles dims [dl*4, dl*4+4)
    int base = lane & 48;          // start lane of this row's 16-lane group

    int start = row_ptr[row];
    int end   = row_ptr[row + 1];

    float ax = 0.f, ay = 0.f, az = 0.f, aw = 0.f;

    int cur = start;
    for (; cur + 16 <= end; cur += 16) {
        u64 e = __builtin_nontemporal_load(ccv + cur + dl);
        int   c = (int)(unsigned int)(e & 0xffffffffu);
        float v = __uint_as_float((unsigned int)(e >> 32));
#pragma unroll
        for (int j = 0; j < 16; ++j) {
            int   cj = __shfl(c, base + j);
            float vj = __shfl(v, base + j);
            ushort4 xb = *reinterpret_cast<const ushort4*>(
                xin + (size_t)cj * EMB_DIM + dl * 4);
            ax += vj * bf2f(xb.x);
            ay += vj * bf2f(xb.y);
            az += vj * bf2f(xb.z);
            aw += vj * bf2f(xb.w);
        }
    }
    int n = end - cur;
    if (n > 0) {
        int   c = 0;
        float v = 0.f;
        if (dl < n) {
            u64 e = ccv[cur + dl];
            c = (int)(unsigned int)(e & 0xffffffffu);
            v = __uint_as_float((unsigned int)(e >> 32));
        }
        for (int j = 0; j < n; ++j) {
            int   cj = __shfl(c, base + j);
            float vj = __shfl(v, base + j);
            ushort4 xb = *reinterpret_cast<const ushort4*>(
                xin + (size_t)cj * EMB_DIM + dl * 4);
            ax += vj * bf2f(xb.x);
            ay += vj * bf2f(xb.y);
            az += vj * bf2f(xb.z);
            aw += vj * bf2f(xb.w);
        }
    }

    ushort4* o = reinterpret_cast<ushort4*>(xout + (size_t)row * EMB_DIM) + dl;
    if (ACCUM) {
        ushort4 old = *o;
        ax += bf2f(old.x); ay += bf2f(old.y); az += bf2f(old.z); aw += bf2f(old.w);
    }
    *o = make_ushort4(f2bf(ax), f2bf(ay), f2bf(az), f2bf(aw));
}

// ---------------------------------------------------------------------------
// 6b) FALLBACK path (small ws): COO edge-parallel atomic scatter, f32.
// ---------------------------------------------------------------------------
template <bool FIRST>
__global__ __launch_bounds__(256) void coo_spmm_kernel(
        const int* __restrict__ rows, const int* __restrict__ cols,
        const float* __restrict__ vals, const float* __restrict__ xin,
        const float* __restrict__ uemb, const float* __restrict__ iemb,
        float* __restrict__ xout) {
    long long e = (long long)blockIdx.x * 16 + (threadIdx.x >> 4);
    int dl = threadIdx.x & 15;
    if (e >= NNZ_C) return;
    int r = rows[e];
    int c = cols[e];
    float v = vals[e];
    const float* src;
    if (FIRST) {
        src = (c < NUM_USERS) ? (uemb + (size_t)c * EMB_DIM)
                              : (iemb + (size_t)(c - NUM_USERS) * EMB_DIM);
    } else {
        src = xin + (size_t)c * EMB_DIM;
    }
    float4 xv = *reinterpret_cast<const float4*>(src + dl * 4);
    float* dst = xout + (size_t)r * EMB_DIM + dl * 4;
    atomicAdd(dst + 0, v * xv.x);
    atomicAdd(dst + 1, v * xv.y);
    atomicAdd(dst + 2, v * xv.z);
    atomicAdd(dst + 3, v * xv.w);
}

// ---------------------------------------------------------------------------
// 7) final: out[b] = dot(acc_u[u], acc_i[i]) / 16   (acc = x0 + A + B)
//    A = x1 + x3 (bf16), B = x2 (bf16), x0 from exact f32 embeddings.
// ---------------------------------------------------------------------------
__global__ __launch_bounds__(256) void dot_bf_kernel(
        const float* __restrict__ uemb, const float* __restrict__ iemb,
        const ushort* __restrict__ A, const ushort* __restrict__ B,
        const int* __restrict__ u_idx, const int* __restrict__ i_idx,
        float* __restrict__ out) {
    int t = blockIdx.x * blockDim.x + threadIdx.x;
    int b = t >> 4;
    int dl = t & 15;
    if (b >= BATCH_C) return;

    int u = u_idx[b];
    int ii = i_idx[b];
    size_t uoff  = (size_t)u * EMB_DIM + dl * 4;
    size_t ioff  = (size_t)ii * EMB_DIM + dl * 4;
    size_t Aioff = (size_t)(NUM_USERS + ii) * EMB_DIM + dl * 4;

    float4 e_u = *reinterpret_cast<const float4*>(uemb + uoff);
    float4 e_i = *reinterpret_cast<const float4*>(iemb + ioff);
    ushort4 a_u = *reinterpret_cast<const ushort4*>(A + uoff);
    ushort4 b_u = *reinterpret_cast<const ushort4*>(B + uoff);
    ushort4 a_i = *reinterpret_cast<const ushort4*>(A + Aioff);
    ushort4 b_i = *reinterpret_cast<const ushort4*>(B + Aioff);

    float ux = e_u.x + bf2f(a_u.x) + bf2f(b_u.x);
    float uy = e_u.y + bf2f(a_u.y) + bf2f(b_u.y);
    float uz = e_u.z + bf2f(a_u.z) + bf2f(b_u.z);
    float uw = e_u.w + bf2f(a_u.w) + bf2f(b_u.w);
    float ix = e_i.x + bf2f(a_i.x) + bf2f(b_i.x);
    float iy = e_i.y + bf2f(a_i.y) + bf2f(b_i.y);
    float iz = e_i.z + bf2f(a_i.z) + bf2f(b_i.z);
    float iw = e_i.w + bf2f(a_i.w) + bf2f(b_i.w);

    float s = ux * ix + uy * iy + uz * iz + uw * iw;
    s += __shfl_xor(s, 1);
    s += __shfl_xor(s, 2);
    s += __shfl_xor(s, 4);
    s += __shfl_xor(s, 8);
    if (dl == 0) out[b] = s * 0.0625f;   // /16 == (acc/4)·(acc/4)
}

__global__ __launch_bounds__(256) void dot_f32_kernel(
        const float* __restrict__ uemb, const float* __restrict__ iemb,
        const float* __restrict__ A, const float* __restrict__ B,
        const int* __restrict__ u_idx, const int* __restrict__ i_idx,
        float* __restrict__ out) {
    int t = blockIdx.x * blockDim.x + threadIdx.x;
    int b = t >> 4;
    int dl = t & 15;
    if (b >= BATCH_C) return;

    int u = u_idx[b];
    int ii = i_idx[b];
    size_t uoff  = (size_t)u * EMB_DIM + dl * 4;
    size_t ioff  = (size_t)ii * EMB_DIM + dl * 4;
    size_t Aioff = (size_t)(NUM_USERS + ii) * EMB_DIM + dl * 4;

    float4 e_u = *reinterpret_cast<const float4*>(uemb + uoff);
    float4 a_u = *reinterpret_cast<const float4*>(A + uoff);
    float4 b_u = *reinterpret_cast<const float4*>(B + uoff);
    float4 e_i = *reinterpret_cast<const float4*>(iemb + ioff);
    float4 a_i = *reinterpret_cast<const float4*>(A + Aioff);
    float4 b_i = *reinterpret_cast<const float4*>(B + Aioff);

    float ux = e_u.x + a_u.x + b_u.x, uy = e_u.y + a_u.y + b_u.y;
    float uz = e_u.z + a_u.z + b_u.z, uw = e_u.w + a_u.w + b_u.w;
    float ix = e_i.x + a_i.x + b_i.x, iy = e_i.y + a_i.y + b_i.y;
    float iz = e_i.z + a_i.z + b_i.z, iw = e_i.w + a_i.w + b_i.w;

    float s = ux * ix + uy * iy + uz * iz + uw * iw;
    s += __shfl_xor(s, 1);
    s += __shfl_xor(s, 2);
    s += __shfl_xor(s, 4);
    s += __shfl_xor(s, 8);
    if (dl == 0) out[b] = s * 0.0625f;
}

// ---------------------------------------------------------------------------
extern "C" void kernel_launch(void* const* d_in, const int* in_sizes, int n_in,
                              void* d_out, int out_size, void* d_ws, size_t ws_size,
                              hipStream_t stream) {
    const float* uemb     = (const float*)d_in[0];
    const float* iemb     = (const float*)d_in[1];
    const float* adj_vals = (const float*)d_in[2];
    const int*   adj_rows = (const int*)d_in[3];
    const int*   adj_cols = (const int*)d_in[4];
    const int*   u_idx    = (const int*)d_in[5];
    const int*   i_idx    = (const int*)d_in[6];
    float* out = (float*)d_out;
    (void)in_sizes; (void)n_in; (void)out_size;

    const size_t DENSE_BF = (size_t)NNODES * EMB_DIM * 2;   // 38.4 MB
    const size_t DENSE_F32 = (size_t)NNODES * EMB_DIM * 4;  // 76.8 MB
    const size_t ALIGN  = 256;
    auto rnd = [&](size_t b) { return (b + ALIGN - 1) & ~(ALIGN - 1); };

    const size_t need_full = rnd(DENSE_BF) * 3 + rnd((size_t)NNZ_C * 8) +
                             rnd((size_t)(NNODES + 1) * 4) + rnd((size_t)NNODES * 4) +
                             rnd(1024 * 4);                  // ~198 MB
    const size_t need_min  = rnd(DENSE_F32) * 2;             // ~154 MB (f32 COO fallback)

    const long long dense_elems = (long long)NNODES * EMB_DIM;
    const int dot_grid = (BATCH_C * 16 + 255) / 256;

    if (ws_size >= need_full) {
        // ------------------- CSR + bf16-state path -------------------
        size_t off = 0;
        auto alloc = [&](size_t bytes) -> void* {
            void* p = (char*)d_ws + off;
            off += rnd(bytes);
            return p;
        };
        ushort* X0      = (ushort*)alloc(DENSE_BF);
        ushort* A       = (ushort*)alloc(DENSE_BF);
        ushort* B       = (ushort*)alloc(DENSE_BF);
        u64*    ccv     = (u64*)   alloc((size_t)NNZ_C * 8);
        int*    row_ptr = (int*)   alloc((size_t)(NNODES + 1) * 4);
        int*    cursor  = (int*)   alloc((size_t)NNODES * 4);
        int*    bsum    = (int*)   alloc(1024 * 4);

        const int nblk_scan = (NNODES + 1023) / 1024;   // 293

        zero_int_kernel<<<(NNODES + 255) / 256, 256, 0, stream>>>(cursor, NNODES);
        convert_x0_kernel<<<2048, 256, 0, stream>>>(uemb, iemb, X0);
        hist_kernel<<<2048, 256, 0, stream>>>(adj_rows, cursor);
        scan_a<<<nblk_scan, 256, 0, stream>>>(cursor, row_ptr, bsum);
        scan_b<<<1, 512, 0, stream>>>(bsum, nblk_scan);
        scan_c<<<(NNODES + 255) / 256, 256, 0, stream>>>(row_ptr, bsum, cursor);
        scatter_kernel<<<2048, 256, 0, stream>>>(adj_rows, adj_cols, adj_vals,
                                                 cursor, ccv);

        const int spmm_grid = NNODES / 16;   // 18750
        spmm_bf_kernel<false><<<spmm_grid, 256, 0, stream>>>(row_ptr, ccv, X0, A);
        spmm_bf_kernel<false><<<spmm_grid, 256, 0, stream>>>(row_ptr, ccv, A, B);
        spmm_bf_kernel<true ><<<spmm_grid, 256, 0, stream>>>(row_ptr, ccv, B, A);

        dot_bf_kernel<<<dot_grid, 256, 0, stream>>>(uemb, iemb, A, B, u_idx, i_idx, out);
    } else if (ws_size >= need_min) {
        // ------------------- COO atomic fallback (small ws, f32) -------------------
        float* A = (float*)d_ws;                           // x1, then x1+x3
        float* B = (float*)((char*)d_ws + rnd(DENSE_F32)); // x2
        const int coo_grid = (NNZ_C + 15) / 16;            // 16 edges/block

        zero_f32_kernel<<<2048, 256, 0, stream>>>(A, dense_elems);
        coo_spmm_kernel<true ><<<coo_grid, 256, 0, stream>>>(adj_rows, adj_cols, adj_vals,
                                                             nullptr, uemb, iemb, A);
        zero_f32_kernel<<<2048, 256, 0, stream>>>(B, dense_elems);
        coo_spmm_kernel<false><<<coo_grid, 256, 0, stream>>>(adj_rows, adj_cols, adj_vals,
                                                             A, nullptr, nullptr, B);
        coo_spmm_kernel<false><<<coo_grid, 256, 0, stream>>>(adj_rows, adj_cols, adj_vals,
                                                             B, nullptr, nullptr, A);

        dot_f32_kernel<<<dot_grid, 256, 0, stream>>>(uemb, iemb, A, B, u_idx, i_idx, out);
    }
    // else: insufficient workspace — launch nothing; harness reports mismatch
    // (diagnostic outcome rather than a container crash).
}